// Round 6
// baseline (1117.067 us; speedup 1.0000x reference)
//
#include <hip/hip_runtime.h>
#include <cmath>

// ---------------------------------------------------------------------------
// Fused 3D SSIM, separable Gaussian 11-tap, VALID. fp32 (2,1,192,192,192).
// z-streaming slab, all-resident grid (1152 blocks, ~26.9 KB LDS -> 5-6
// blocks/CU, single dispatch round). Per plane:
//   stage: global->LDS raw plane, (img1,img2) interleaved float2 (each input
//          element read once per block)  | barrier
//   W    : raw->tws, 5 channels from packed pairs, x-pair outputs | barrier
//   H    : tws->regs (y-major, bank-perfect, read2-mergeable)
//   D    : register shift-FMA pipeline (packed), fused SSIM + reduction.
// All addressing hoisted out of the z-loop. Workspace use: 16 bytes.
// ---------------------------------------------------------------------------

#define WSZ 11
#define DIN 192
#define DOUTS 182
#define TH 16              // tile height (output rows, y)
#define TWD 32             // tile width  (output cols, x)
#define IHR 26             // input rows per plane tile (TH + 10)
#define RPAD 46            // raw row pad (float2 units, even -> b128 align)
#define HPAD 27            // tws h-dim pad (bank stagger)
#define ZCH 24             // output planes per chunk
#define ZIN 34             // max input planes per chunk
#define NTX 6              // x tiles (6*32 = 192)
#define NTY 12             // y tiles (12*16 = 192)
#define ZC 8               // z-chunks (8*24 = 192)
#define NBLK (NTX*NTY*2*ZC)   // 1152
#define NSITE (IHR*21)        // 546 stage sites (26 rows x 21 float2-cols)
#define PLANE (DIN*DIN)       // 36864
static constexpr double SOUT = 2.0 * 182.0 * 182.0 * 182.0;  // 12,057,136

typedef float v2f __attribute__((ext_vector_type(2)));

struct G11 { float g[WSZ]; };

__device__ __forceinline__ v2f pkfma(float g, v2f v, v2f a) {
    return __builtin_elementwise_fma((v2f){g, g}, v, a);
}

__device__ __forceinline__ unsigned int enc_f(float f) {
    unsigned int u = __float_as_uint(f);
    return (u & 0x80000000u) ? ~u : (u | 0x80000000u);
}
__device__ __forceinline__ float dec_f(unsigned int u) {
    return (u & 0x80000000u) ? __uint_as_float(u & 0x7FFFFFFFu) : __uint_as_float(~u);
}

// ---------------------------------------------------------------------------
__global__ void k_init(unsigned int* mm, double* sum) {
    sum[0] = 0.0;
    mm[0] = 0u;           // encoded -inf (max accumulator)
    mm[1] = 0xFFFFFFFFu;  // encoded +inf (min accumulator)
}

// ---------------------------------------------------------------------------
__global__ __launch_bounds__(256) void k_minmax(const float4* __restrict__ img1,
                                                int n4, unsigned int* mm) {
    float mx = -1e30f, mn = 1e30f;
    for (int i = blockIdx.x * blockDim.x + threadIdx.x; i < n4;
         i += gridDim.x * blockDim.x) {
        float4 v = img1[i];
        mx = fmaxf(mx, fmaxf(fmaxf(v.x, v.y), fmaxf(v.z, v.w)));
        mn = fminf(mn, fminf(fminf(v.x, v.y), fminf(v.z, v.w)));
    }
    #pragma unroll
    for (int o = 32; o; o >>= 1) {
        mx = fmaxf(mx, __shfl_down(mx, o));
        mn = fminf(mn, __shfl_down(mn, o));
    }
    __shared__ float smx[4], smn[4];
    int lane = threadIdx.x & 63, wv = threadIdx.x >> 6;
    if (lane == 0) { smx[wv] = mx; smn[wv] = mn; }
    __syncthreads();
    if (threadIdx.x == 0) {
        #pragma unroll
        for (int i = 1; i < 4; i++) { mx = fmaxf(mx, smx[i]); mn = fminf(mn, smn[i]); }
        atomicMax(&mm[0], enc_f(mx));
        atomicMin(&mm[1], enc_f(mn));
    }
}

// ---------------------------------------------------------------------------
__global__ __launch_bounds__(256, 4) void k_ssim(const float* __restrict__ img1,
                                                 const float* __restrict__ img2,
                                                 const unsigned int* __restrict__ mm,
                                                 double* __restrict__ sum, G11 gw) {
    __shared__ float2 raw[IHR][RPAD];      // (img1,img2) interleaved, 9.6 KB
    __shared__ float2 tws[5][16][HPAD];    // W-out, y-major x-pairs, 17.3 KB
    __shared__ float  sred[4];

    int b    = blockIdx.x;
    int twi  = b % NTX;
    int thi  = (b / NTX) % NTY;
    int rest = b / (NTX * NTY);
    int tc   = rest % ZC;
    int n    = rest / ZC;                  // batch 0..1
    int ow0 = twi * TWD, oh0 = thi * TH, od0 = tc * ZCH;
    int tid = threadIdx.x;
    int y = tid & 15, xg = tid >> 4;       // H/D mapping: y fast (bank-perfect)
    int zin = min(ZIN, DIN - od0);         // last chunk: 24 planes

    // ---- hoisted stage-site coords (3 strided items) ----
    int soff[3], slds[3];
    bool sval[3];
    #pragma unroll
    for (int it = 0; it < 3; it++) {
        int u = tid + it * 256;
        sval[it] = (u < NSITE);
        int uu = sval[it] ? u : 0;
        int row = uu / 21, col = uu - row * 21;
        int hr = min(oh0 + row, DIN - 1);      // clamped rows feed masked oh
        int s  = min(ow0 + 2 * col, DIN - 2);  // clamped cols feed masked ow
        soff[it] = hr * DIN + s;               // in-plane element offset (even)
        slds[it] = row * RPAD + 2 * col;       // float2 index in raw
    }

    // ---- hoisted W-item coords (2 strided items over 416 = 26x16) ----
    int wh0 = tid >> 4,          wxp0 = tid & 15;   // h 0..15
    int wh1 = (tid + 256) >> 4,  wxp1 = tid & 15;   // h 16..25
    bool wv1 = (tid < IHR * 16 - 256);              // tid < 160

    int pbase = (n * DIN + od0) * PLANE;   // uniform; bumped by PLANE per zi

    // ---- SSIM constants (L from img1 min/max via k_minmax) ----
    float maxv = dec_f(mm[0]);
    float minv = dec_f(mm[1]);
    float max_val = (maxv > 128.0f) ? 255.0f : 1.0f;
    float min_val = (minv < -0.5f) ? -1.0f : 0.0f;
    float L  = max_val - min_val;
    float C1 = 0.01f * L; C1 *= C1;
    float C2 = 0.03f * L; C2 *= C2;

    bool vy  = (oh0 + y < DOUTS);
    bool vx0 = vy && (ow0 + 2 * xg     < DOUTS);
    bool vx1 = vy && (ow0 + 2 * xg + 1 < DOUTS);

    v2f acc[5][WSZ];
    #pragma unroll
    for (int c = 0; c < 5; c++)
        #pragma unroll
        for (int j = 0; j < WSZ; j++) acc[c][j] = (v2f){0.f, 0.f};
    float local = 0.f;
    float2* rawf = &raw[0][0];

    for (int zi = 0; zi < zin; zi++) {
        // ---- stage: global -> raw LDS, interleaved (i1,i2) ----
        #pragma unroll
        for (int it = 0; it < 3; it++) {
            if (sval[it]) {
                float2 f1 = *(const float2*)(img1 + pbase + soff[it]);
                float2 f2 = *(const float2*)(img2 + pbase + soff[it]);
                *(float4*)&rawf[slds[it]] = make_float4(f1.x, f2.x, f1.y, f2.y);
            }
        }
        pbase += PLANE;
        __syncthreads();

        // ---- W: raw -> tws, 5 channels, x-pair outputs ----
        {
            auto do_w = [&](int h, int xp) {
                const float4* rb = (const float4*)&rawf[h * RPAD + 2 * xp];
                v2f e[12];                     // e[x] = (img1[x], img2[x])
                #pragma unroll
                for (int q = 0; q < 6; q++) {
                    float4 f = rb[q];
                    e[2*q]   = (v2f){f.x, f.y};
                    e[2*q+1] = (v2f){f.z, f.w};
                }
                v2f amu[2] = {{0.f,0.f},{0.f,0.f}};   // (mu1, mu2)
                v2f asq[2] = {{0.f,0.f},{0.f,0.f}};   // (E11, E22)
                float a12[2] = {0.f, 0.f};            // E12
                #pragma unroll
                for (int k = 0; k < WSZ; k++) {
                    float g = gw.g[k];
                    #pragma unroll
                    for (int o = 0; o < 2; o++) {
                        v2f ee = e[k + o];
                        v2f t  = (v2f){g, g} * ee;
                        amu[o] += t;
                        asq[o] = __builtin_elementwise_fma(t, ee, asq[o]);
                        a12[o] = fmaf(t.x, ee.y, a12[o]);
                    }
                }
                tws[0][xp][h] = make_float2(amu[0].x, amu[1].x);
                tws[1][xp][h] = make_float2(amu[0].y, amu[1].y);
                tws[2][xp][h] = make_float2(asq[0].x, asq[1].x);
                tws[3][xp][h] = make_float2(asq[0].y, asq[1].y);
                tws[4][xp][h] = make_float2(a12[0],   a12[1]);
            };
            do_w(wh0, wxp0);
            if (wv1) do_w(wh1, wxp1);
        }
        __syncthreads();

        // ---- H: tws -> m[5] (taps contiguous in LDS, read2-mergeable) ----
        v2f m[5];
        #pragma unroll
        for (int c = 0; c < 5; c++) {
            v2f a = {0.f, 0.f};
            #pragma unroll
            for (int k = 0; k < WSZ; k++) {
                float2 t = tws[c][xg][y + k];
                a = pkfma(gw.g[k], (v2f){t.x, t.y}, a);
            }
            m[c] = a;
        }

        // ---- D shift-FMA (packed): acc[j] = g[j]*m + acc[j-1] ----
        #pragma unroll
        for (int c = 0; c < 5; c++) {
            #pragma unroll
            for (int j = WSZ - 1; j >= 1; j--)
                acc[c][j] = pkfma(gw.g[j], m[c], acc[c][j-1]);
            acc[c][0] = (v2f){gw.g[0], gw.g[0]} * m[c];
        }

        // ---- SSIM for completed plane (zo always < DOUTS given zin trim) ----
        if (zi >= WSZ - 1) {
            v2f mu1 = acc[0][10], mu2 = acc[1][10];
            v2f mu1s = mu1 * mu1, mu2s = mu2 * mu2, mu12 = mu1 * mu2;
            v2f s1  = acc[2][10] - mu1s;
            v2f s2  = acc[3][10] - mu2s;
            v2f s12 = acc[4][10] - mu12;
            v2f c2v = {C2, C2};
            v2f v1  = (v2f){2.f, 2.f} * s12 + c2v;
            v2f v2  = s1 + s2 + c2v;
            v2f c1v = {C1, C1};
            v2f num = ((v2f){2.f, 2.f} * mu12 + c1v) * v1;
            v2f den = (mu1s + mu2s + c1v) * v2;
            v2f ss  = num / den;
            if (vx0) local += ss.x;
            if (vx1) local += ss.y;
        }
    }

    // ---- block reduction -> one f64 atomic ----
    #pragma unroll
    for (int o = 32; o; o >>= 1) local += __shfl_down(local, o);
    if ((tid & 63) == 0) sred[tid >> 6] = local;
    __syncthreads();
    if (tid == 0)
        atomicAdd(sum, (double)(sred[0] + sred[1] + sred[2] + sred[3]));
}

// ---------------------------------------------------------------------------
__global__ void k_final(const double* __restrict__ sum, float* __restrict__ out) {
    out[0] = (float)(sum[0] / SOUT);
}

// ---------------------------------------------------------------------------
extern "C" void kernel_launch(void* const* d_in, const int* in_sizes, int n_in,
                              void* d_out, int out_size, void* d_ws, size_t ws_size,
                              hipStream_t stream) {
    const float* img1 = (const float*)d_in[0];
    const float* img2 = (const float*)d_in[1];
    float* out = (float*)d_out;

    char* ws = (char*)d_ws;
    double*       sum = (double*)ws;              // 8 B
    unsigned int* mm  = (unsigned int*)(ws + 8);  // 8 B

    // Gaussian weights: f64 compute, normalize, cast to f32 (matches ref).
    G11 g;
    {
        double gd[WSZ], s = 0.0;
        for (int i = 0; i < WSZ; i++) {
            double d = (double)(i - WSZ / 2);
            gd[i] = std::exp(-(d * d) / (2.0 * 1.5 * 1.5));
            s += gd[i];
        }
        for (int i = 0; i < WSZ; i++) g.g[i] = (float)(gd[i] / s);
    }

    int n_img = 2 * DIN * DIN * DIN;  // 14,155,776

    k_init<<<1, 1, 0, stream>>>(mm, sum);
    k_minmax<<<2048, 256, 0, stream>>>((const float4*)img1, n_img / 4, mm);
    k_ssim<<<NBLK, 256, 0, stream>>>(img1, img2, mm, sum, g);
    k_final<<<1, 1, 0, stream>>>(sum, out);
}

// Round 7
// 655.810 us; speedup vs baseline: 1.7033x; 1.7033x over previous
//
#include <hip/hip_runtime.h>
#include <cmath>

// ---------------------------------------------------------------------------
// Fused 3D SSIM, separable Gaussian 11-tap, VALID. fp32 (2,1,192,192,192).
// z-streaming slab, all-resident grid (1152 blocks, ~26.9 KB LDS). Per plane:
//   stage: global->LDS raw plane, (img1,img2) interleaved float2 (each input
//          element read once per block)  | barrier
//   W    : raw->tws, 5 channels from packed pairs, x-pair outputs | barrier
//   H    : tws->regs (y-major, bank-balanced)
//   D    : register shift-FMA pipeline (packed), fused SSIM + reduction.
// All addressing hoisted out of the z-loop. Workspace use: 16 bytes.
//
// __launch_bounds__(256,3): r6 used (256,4) and the allocator spilled the
// acc[5][11] v2f accumulator to scratch (WRITE_SIZE 2 GB, 4x regression).
// (256,3) is the r5-proven allocation (VGPR 84, acc in unified AGPR half,
// zero spill). DO NOT tighten this again.
// ---------------------------------------------------------------------------

#define WSZ 11
#define DIN 192
#define DOUTS 182
#define TH 16              // tile height (output rows, y)
#define TWD 32             // tile width  (output cols, x)
#define IHR 26             // input rows per plane tile (TH + 10)
#define RPAD 46            // raw row pad (float2 units, even -> b128 align)
#define HPAD 27            // tws h-dim pad (bank stagger)
#define ZCH 24             // output planes per chunk
#define ZIN 34             // max input planes per chunk
#define NTX 6              // x tiles (6*32 = 192)
#define NTY 12             // y tiles (12*16 = 192)
#define ZC 8               // z-chunks (8*24 = 192)
#define NBLK (NTX*NTY*2*ZC)   // 1152
#define NSITE (IHR*21)        // 546 stage sites (26 rows x 21 float2-cols)
#define PLANE (DIN*DIN)       // 36864
static constexpr double SOUT = 2.0 * 182.0 * 182.0 * 182.0;  // 12,057,136

typedef float v2f __attribute__((ext_vector_type(2)));

struct G11 { float g[WSZ]; };

__device__ __forceinline__ v2f pkfma(float g, v2f v, v2f a) {
    return __builtin_elementwise_fma((v2f){g, g}, v, a);
}

__device__ __forceinline__ unsigned int enc_f(float f) {
    unsigned int u = __float_as_uint(f);
    return (u & 0x80000000u) ? ~u : (u | 0x80000000u);
}
__device__ __forceinline__ float dec_f(unsigned int u) {
    return (u & 0x80000000u) ? __uint_as_float(u & 0x7FFFFFFFu) : __uint_as_float(~u);
}

// ---------------------------------------------------------------------------
__global__ void k_init(unsigned int* mm, double* sum) {
    sum[0] = 0.0;
    mm[0] = 0u;           // encoded -inf (max accumulator)
    mm[1] = 0xFFFFFFFFu;  // encoded +inf (min accumulator)
}

// ---------------------------------------------------------------------------
__global__ __launch_bounds__(256) void k_minmax(const float4* __restrict__ img1,
                                                int n4, unsigned int* mm) {
    float mx = -1e30f, mn = 1e30f;
    for (int i = blockIdx.x * blockDim.x + threadIdx.x; i < n4;
         i += gridDim.x * blockDim.x) {
        float4 v = img1[i];
        mx = fmaxf(mx, fmaxf(fmaxf(v.x, v.y), fmaxf(v.z, v.w)));
        mn = fminf(mn, fminf(fminf(v.x, v.y), fminf(v.z, v.w)));
    }
    #pragma unroll
    for (int o = 32; o; o >>= 1) {
        mx = fmaxf(mx, __shfl_down(mx, o));
        mn = fminf(mn, __shfl_down(mn, o));
    }
    __shared__ float smx[4], smn[4];
    int lane = threadIdx.x & 63, wv = threadIdx.x >> 6;
    if (lane == 0) { smx[wv] = mx; smn[wv] = mn; }
    __syncthreads();
    if (threadIdx.x == 0) {
        #pragma unroll
        for (int i = 1; i < 4; i++) { mx = fmaxf(mx, smx[i]); mn = fminf(mn, smn[i]); }
        atomicMax(&mm[0], enc_f(mx));
        atomicMin(&mm[1], enc_f(mn));
    }
}

// ---------------------------------------------------------------------------
__global__ __launch_bounds__(256, 3) void k_ssim(const float* __restrict__ img1,
                                                 const float* __restrict__ img2,
                                                 const unsigned int* __restrict__ mm,
                                                 double* __restrict__ sum, G11 gw) {
    __shared__ float2 raw[IHR][RPAD];      // (img1,img2) interleaved, 9.6 KB
    __shared__ float2 tws[5][16][HPAD];    // W-out, y-major x-pairs, 17.3 KB
    __shared__ float  sred[4];

    int b    = blockIdx.x;
    int twi  = b % NTX;
    int thi  = (b / NTX) % NTY;
    int rest = b / (NTX * NTY);
    int tc   = rest % ZC;
    int n    = rest / ZC;                  // batch 0..1
    int ow0 = twi * TWD, oh0 = thi * TH, od0 = tc * ZCH;
    int tid = threadIdx.x;
    int y = tid & 15, xg = tid >> 4;       // H/D mapping: y fast (bank-balanced)
    int zin = min(ZIN, DIN - od0);         // last chunk: 24 planes

    // ---- hoisted stage-site coords (3 strided items) ----
    int soff[3], slds[3];
    bool sval[3];
    #pragma unroll
    for (int it = 0; it < 3; it++) {
        int u = tid + it * 256;
        sval[it] = (u < NSITE);
        int uu = sval[it] ? u : 0;
        int row = uu / 21, col = uu - row * 21;
        int hr = min(oh0 + row, DIN - 1);      // clamped rows feed masked oh
        int s  = min(ow0 + 2 * col, DIN - 2);  // clamped cols feed masked ow
        soff[it] = hr * DIN + s;               // in-plane element offset (even)
        slds[it] = row * RPAD + 2 * col;       // float2 index in raw
    }

    // ---- hoisted W-item coords (2 strided items over 416 = 26x16) ----
    int wh0 = tid >> 4,          wxp0 = tid & 15;   // h 0..15
    int wh1 = (tid + 256) >> 4,  wxp1 = tid & 15;   // h 16..25
    bool wv1 = (tid < IHR * 16 - 256);              // tid < 160

    int pbase = (n * DIN + od0) * PLANE;   // uniform; bumped by PLANE per zi

    // ---- SSIM constants (L from img1 min/max via k_minmax) ----
    float maxv = dec_f(mm[0]);
    float minv = dec_f(mm[1]);
    float max_val = (maxv > 128.0f) ? 255.0f : 1.0f;
    float min_val = (minv < -0.5f) ? -1.0f : 0.0f;
    float L  = max_val - min_val;
    float C1 = 0.01f * L; C1 *= C1;
    float C2 = 0.03f * L; C2 *= C2;

    bool vy  = (oh0 + y < DOUTS);
    bool vx0 = vy && (ow0 + 2 * xg     < DOUTS);
    bool vx1 = vy && (ow0 + 2 * xg + 1 < DOUTS);

    v2f acc[5][WSZ];
    #pragma unroll
    for (int c = 0; c < 5; c++)
        #pragma unroll
        for (int j = 0; j < WSZ; j++) acc[c][j] = (v2f){0.f, 0.f};
    float local = 0.f;
    float2* rawf = &raw[0][0];

    for (int zi = 0; zi < zin; zi++) {
        // ---- stage: global -> raw LDS, interleaved (i1,i2) ----
        #pragma unroll
        for (int it = 0; it < 3; it++) {
            if (sval[it]) {
                float2 f1 = *(const float2*)(img1 + pbase + soff[it]);
                float2 f2 = *(const float2*)(img2 + pbase + soff[it]);
                *(float4*)&rawf[slds[it]] = make_float4(f1.x, f2.x, f1.y, f2.y);
            }
        }
        pbase += PLANE;
        __syncthreads();

        // ---- W: raw -> tws, 5 channels, x-pair outputs ----
        {
            auto do_w = [&](int h, int xp) {
                const float4* rb = (const float4*)&rawf[h * RPAD + 2 * xp];
                v2f e[12];                     // e[x] = (img1[x], img2[x])
                #pragma unroll
                for (int q = 0; q < 6; q++) {
                    float4 f = rb[q];
                    e[2*q]   = (v2f){f.x, f.y};
                    e[2*q+1] = (v2f){f.z, f.w};
                }
                v2f amu[2] = {{0.f,0.f},{0.f,0.f}};   // (mu1, mu2)
                v2f asq[2] = {{0.f,0.f},{0.f,0.f}};   // (E11, E22)
                float a12[2] = {0.f, 0.f};            // E12
                #pragma unroll
                for (int k = 0; k < WSZ; k++) {
                    float g = gw.g[k];
                    #pragma unroll
                    for (int o = 0; o < 2; o++) {
                        v2f ee = e[k + o];
                        v2f t  = (v2f){g, g} * ee;
                        amu[o] += t;
                        asq[o] = __builtin_elementwise_fma(t, ee, asq[o]);
                        a12[o] = fmaf(t.x, ee.y, a12[o]);
                    }
                }
                tws[0][xp][h] = make_float2(amu[0].x, amu[1].x);
                tws[1][xp][h] = make_float2(amu[0].y, amu[1].y);
                tws[2][xp][h] = make_float2(asq[0].x, asq[1].x);
                tws[3][xp][h] = make_float2(asq[0].y, asq[1].y);
                tws[4][xp][h] = make_float2(a12[0],   a12[1]);
            };
            do_w(wh0, wxp0);
            if (wv1) do_w(wh1, wxp1);
        }
        __syncthreads();

        // ---- H: tws -> m[5] (taps contiguous in LDS) ----
        v2f m[5];
        #pragma unroll
        for (int c = 0; c < 5; c++) {
            v2f a = {0.f, 0.f};
            #pragma unroll
            for (int k = 0; k < WSZ; k++) {
                float2 t = tws[c][xg][y + k];
                a = pkfma(gw.g[k], (v2f){t.x, t.y}, a);
            }
            m[c] = a;
        }

        // ---- D shift-FMA (packed): acc[j] = g[j]*m + acc[j-1] ----
        #pragma unroll
        for (int c = 0; c < 5; c++) {
            #pragma unroll
            for (int j = WSZ - 1; j >= 1; j--)
                acc[c][j] = pkfma(gw.g[j], m[c], acc[c][j-1]);
            acc[c][0] = (v2f){gw.g[0], gw.g[0]} * m[c];
        }

        // ---- SSIM for completed plane (zo always < DOUTS given zin trim) ----
        if (zi >= WSZ - 1) {
            v2f mu1 = acc[0][10], mu2 = acc[1][10];
            v2f mu1s = mu1 * mu1, mu2s = mu2 * mu2, mu12 = mu1 * mu2;
            v2f s1  = acc[2][10] - mu1s;
            v2f s2  = acc[3][10] - mu2s;
            v2f s12 = acc[4][10] - mu12;
            v2f c2v = {C2, C2};
            v2f v1  = (v2f){2.f, 2.f} * s12 + c2v;
            v2f v2  = s1 + s2 + c2v;
            v2f c1v = {C1, C1};
            v2f num = ((v2f){2.f, 2.f} * mu12 + c1v) * v1;
            v2f den = (mu1s + mu2s + c1v) * v2;
            v2f ss  = num / den;
            if (vx0) local += ss.x;
            if (vx1) local += ss.y;
        }
    }

    // ---- block reduction -> one f64 atomic ----
    #pragma unroll
    for (int o = 32; o; o >>= 1) local += __shfl_down(local, o);
    if ((tid & 63) == 0) sred[tid >> 6] = local;
    __syncthreads();
    if (tid == 0)
        atomicAdd(sum, (double)(sred[0] + sred[1] + sred[2] + sred[3]));
}

// ---------------------------------------------------------------------------
__global__ void k_final(const double* __restrict__ sum, float* __restrict__ out) {
    out[0] = (float)(sum[0] / SOUT);
}

// ---------------------------------------------------------------------------
extern "C" void kernel_launch(void* const* d_in, const int* in_sizes, int n_in,
                              void* d_out, int out_size, void* d_ws, size_t ws_size,
                              hipStream_t stream) {
    const float* img1 = (const float*)d_in[0];
    const float* img2 = (const float*)d_in[1];
    float* out = (float*)d_out;

    char* ws = (char*)d_ws;
    double*       sum = (double*)ws;              // 8 B
    unsigned int* mm  = (unsigned int*)(ws + 8);  // 8 B

    // Gaussian weights: f64 compute, normalize, cast to f32 (matches ref).
    G11 g;
    {
        double gd[WSZ], s = 0.0;
        for (int i = 0; i < WSZ; i++) {
            double d = (double)(i - WSZ / 2);
            gd[i] = std::exp(-(d * d) / (2.0 * 1.5 * 1.5));
            s += gd[i];
        }
        for (int i = 0; i < WSZ; i++) g.g[i] = (float)(gd[i] / s);
    }

    int n_img = 2 * DIN * DIN * DIN;  // 14,155,776

    k_init<<<1, 1, 0, stream>>>(mm, sum);
    k_minmax<<<2048, 256, 0, stream>>>((const float4*)img1, n_img / 4, mm);
    k_ssim<<<NBLK, 256, 0, stream>>>(img1, img2, mm, sum, g);
    k_final<<<1, 1, 0, stream>>>(sum, out);
}

// Round 8
// 361.355 us; speedup vs baseline: 3.0913x; 1.8149x over previous
//
#include <hip/hip_runtime.h>
#include <cmath>

// ---------------------------------------------------------------------------
// Fused 3D SSIM, separable Gaussian 11-tap, VALID. fp32 (2,1,192,192,192).
// z-streaming slab, x-paired threads + packed-fp32 (v_pk_fma_f32) math:
//   tile 32(x) x 16(y), 256 threads, thread owns x-pair; acc[5][11] float2.
//   W-phase packs (img1,img2) as the vector lane-pair; H-phase reads LDS as
//   ds_read_b64; D-conv is a packed shift-FMA pipeline.
//
// This is the round-5 kernel (proven spill-free allocation: VGPR 84,
// WRITE_SIZE ~1 MB) with exactly ONE change: tws is single-buffered
// (16.6 KB instead of 33.3 KB) with a second __syncthreads() per plane.
// That lifts LDS-capacity from 4 to 6+ blocks/CU so the 1152-block grid is
// fully resident in one dispatch round (r5 measured 26% occupancy from
// two-round quantization).
//
// DO NOT: tighten launch bounds below (256,3) [r6: acc spills, 4x regression]
// DO NOT: add hoisted per-thread address arrays / restructure W into lambdas
//         [r7: pushed live set over the edge, acc spilled 510 MB]
// ---------------------------------------------------------------------------

#define WSZ 11
#define DIN 192
#define DOUTS 182
#define TH 16              // tile height (output rows, y)
#define TWD 32             // tile width  (output cols, x)
#define IHR 26             // input rows per plane tile (TH + 10)
#define ZCH 24             // output planes per chunk
#define ZIN 34             // input planes per chunk (ZCH + 10)
#define NTX 6              // x tiles (6*32 = 192)
#define NTY 12             // y tiles (12*16 = 192)
#define ZC 8               // z-chunks (8*24 = 192)
#define NBLK (NTX*NTY*2*ZC)  // 1152
static constexpr double SOUT = 2.0 * 182.0 * 182.0 * 182.0;  // 12,057,136

typedef float v2f __attribute__((ext_vector_type(2)));

struct G11 { float g[WSZ]; };

__device__ __forceinline__ v2f pkfma(float g, v2f v, v2f a) {
    v2f gg = {g, g};
    return __builtin_elementwise_fma(gg, v, a);
}

__device__ __forceinline__ unsigned int enc_f(float f) {
    unsigned int u = __float_as_uint(f);
    return (u & 0x80000000u) ? ~u : (u | 0x80000000u);
}
__device__ __forceinline__ float dec_f(unsigned int u) {
    return (u & 0x80000000u) ? __uint_as_float(u & 0x7FFFFFFFu) : __uint_as_float(~u);
}

// ---------------------------------------------------------------------------
__global__ void k_init(unsigned int* mm, double* sum) {
    sum[0] = 0.0;
    mm[0] = 0u;           // encoded -inf (max accumulator)
    mm[1] = 0xFFFFFFFFu;  // encoded +inf (min accumulator)
}

// ---------------------------------------------------------------------------
__global__ __launch_bounds__(256) void k_minmax(const float4* __restrict__ img1,
                                                int n4, unsigned int* mm) {
    float mx = -1e30f, mn = 1e30f;
    for (int i = blockIdx.x * blockDim.x + threadIdx.x; i < n4;
         i += gridDim.x * blockDim.x) {
        float4 v = img1[i];
        mx = fmaxf(mx, fmaxf(fmaxf(v.x, v.y), fmaxf(v.z, v.w)));
        mn = fminf(mn, fminf(fminf(v.x, v.y), fminf(v.z, v.w)));
    }
    #pragma unroll
    for (int o = 32; o; o >>= 1) {
        mx = fmaxf(mx, __shfl_down(mx, o));
        mn = fminf(mn, __shfl_down(mn, o));
    }
    __shared__ float smx[4], smn[4];
    int lane = threadIdx.x & 63, wv = threadIdx.x >> 6;
    if (lane == 0) { smx[wv] = mx; smn[wv] = mn; }
    __syncthreads();
    if (threadIdx.x == 0) {
        #pragma unroll
        for (int i = 1; i < 4; i++) { mx = fmaxf(mx, smx[i]); mn = fminf(mn, smn[i]); }
        atomicMax(&mm[0], enc_f(mx));
        atomicMin(&mm[1], enc_f(mn));
    }
}

// ---------------------------------------------------------------------------
// launch_bounds(256, 3): VGPR cap ~170; r5-proven spill-free (VGPR 84).
__global__ __launch_bounds__(256, 3) void k_ssim(const float* __restrict__ img1,
                                                 const float* __restrict__ img2,
                                                 const unsigned int* __restrict__ mm,
                                                 double* __restrict__ sum, G11 gw) {
    __shared__ float tws[5][IHR][TWD];  // single-buffered W-conv plane, 16.6 KB
    __shared__ float sred[4];

    int b   = blockIdx.x;
    int twi = b % NTX;
    int thi = (b / NTX) % NTY;
    int rest = b / (NTX * NTY);
    int tc  = rest % ZC;
    int n   = rest / ZC;                 // batch 0..1
    int ow0 = twi * TWD, oh0 = thi * TH, od0 = tc * ZCH;
    int tid = threadIdx.x;
    int y = tid >> 4, xg = tid & 15;     // thread owns outputs (y, 2xg), (y, 2xg+1)
    int x0 = 2 * xg;

    // SSIM constants (L from img1 min/max, computed by k_minmax)
    float maxv = dec_f(mm[0]);
    float minv = dec_f(mm[1]);
    float max_val = (maxv > 128.0f) ? 255.0f : 1.0f;
    float min_val = (minv < -0.5f) ? -1.0f : 0.0f;
    float L  = max_val - min_val;
    float C1 = 0.01f * L; C1 *= C1;
    float C2 = 0.03f * L; C2 *= C2;

    bool vy  = (oh0 + y < DOUTS);
    bool vx0 = vy && (ow0 + x0 < DOUTS);
    bool vx1 = vy && (ow0 + x0 + 1 < DOUTS);

    // D-conv packed shift pipeline: acc[c][j] covers output zo = zi - j.
    v2f acc[5][WSZ];
    float local = 0.f;

    for (int zi = 0; zi < ZIN; zi++) {
        int d = min(od0 + zi, DIN - 1);  // clamped planes feed only masked zo

        // ---- W phase: 416 pair-items (h in [0,26), xp in [0,16)) ----
        for (int u = tid; u < IHR * 16; u += 256) {
            int h = u >> 4, xp = u & 15;
            int hr = min(oh0 + h, DIN - 1);          // clamped rows -> masked oh
            int s  = min(ow0 + 2 * xp, DIN - 12);    // even, loads stay in-bounds
            const float2* p1 = (const float2*)(img1 + (((n * DIN + d) * DIN + hr) * DIN + s));
            const float2* p2 = (const float2*)(img2 + (((n * DIN + d) * DIN + hr) * DIN + s));
            v2f p[12];                               // lane-pair = (img1, img2)
            #pragma unroll
            for (int q = 0; q < 6; q++) {
                float2 f1 = p1[q];
                float2 f2 = p2[q];
                p[2*q]   = (v2f){f1.x, f2.x};
                p[2*q+1] = (v2f){f1.y, f2.y};
            }
            v2f amu[2] = {{0.f,0.f},{0.f,0.f}};      // (mu1, mu2) per output
            v2f asq[2] = {{0.f,0.f},{0.f,0.f}};      // (E11, E22) per output
            float a12[2] = {0.f, 0.f};               // E12 per output
            #pragma unroll
            for (int k = 0; k < WSZ; k++) {
                float g = gw.g[k];
                #pragma unroll
                for (int o = 0; o < 2; o++) {
                    v2f e = p[k + o];
                    v2f t = (v2f){g, g} * e;         // pk_mul
                    amu[o] += t;                     // pk_add
                    asq[o] = __builtin_elementwise_fma(t, e, asq[o]);  // pk_fma
                    a12[o] = fmaf(t.x, e.y, a12[o]); // cross term
                }
            }
            int xo = 2 * xp;
            *(v2f*)&tws[0][h][xo] = (v2f){amu[0].x, amu[1].x};
            *(v2f*)&tws[1][h][xo] = (v2f){amu[0].y, amu[1].y};
            *(v2f*)&tws[2][h][xo] = (v2f){asq[0].x, asq[1].x};
            *(v2f*)&tws[3][h][xo] = (v2f){asq[0].y, asq[1].y};
            *(v2f*)&tws[4][h][xo] = (v2f){a12[0],   a12[1]};
        }
        __syncthreads();   // W writes visible before H reads

        // ---- H phase: packed over the x-pair, ds_read_b64 per (c,k) ----
        v2f m[5];
        #pragma unroll
        for (int c = 0; c < 5; c++) {
            v2f a = {0.f, 0.f};
            #pragma unroll
            for (int k = 0; k < WSZ; k++) {
                v2f vv = *(const v2f*)&tws[c][y + k][x0];
                a = pkfma(gw.g[k], vv, a);
            }
            m[c] = a;
        }
        __syncthreads();   // H reads done before next plane's W overwrites tws

        // ---- D shift-FMA (packed): acc[j] = g[j]*m + acc[j-1] ----
        #pragma unroll
        for (int c = 0; c < 5; c++) {
            #pragma unroll
            for (int j = WSZ - 1; j >= 1; j--)
                acc[c][j] = pkfma(gw.g[j], m[c], acc[c][j-1]);
            acc[c][0] = (v2f){gw.g[0], gw.g[0]} * m[c];
        }

        // ---- SSIM for completed output plane zo = zi - 10 ----
        if (zi >= WSZ - 1) {
            int zo = od0 + zi - (WSZ - 1);
            if (zo < DOUTS) {            // uniform branch
                v2f mu1 = acc[0][10], mu2 = acc[1][10];
                v2f mu1s = mu1 * mu1, mu2s = mu2 * mu2, mu12 = mu1 * mu2;
                v2f s1  = acc[2][10] - mu1s;
                v2f s2  = acc[3][10] - mu2s;
                v2f s12 = acc[4][10] - mu12;
                v2f c2v = {C2, C2};
                v2f v1  = (v2f){2.f,2.f} * s12 + c2v;
                v2f v2  = s1 + s2 + c2v;
                v2f c1v = {C1, C1};
                v2f num = ((v2f){2.f,2.f} * mu12 + c1v) * v1;
                v2f den = (mu1s + mu2s + c1v) * v2;
                v2f ss  = num / den;
                if (vx0) local += ss.x;
                if (vx1) local += ss.y;
            }
        }
    }

    // ---- block reduction -> one f64 atomic ----
    #pragma unroll
    for (int o = 32; o; o >>= 1) local += __shfl_down(local, o);
    if ((tid & 63) == 0) sred[tid >> 6] = local;
    __syncthreads();
    if (tid == 0)
        atomicAdd(sum, (double)(sred[0] + sred[1] + sred[2] + sred[3]));
}

// ---------------------------------------------------------------------------
__global__ void k_final(const double* __restrict__ sum, float* __restrict__ out) {
    out[0] = (float)(sum[0] / SOUT);
}

// ---------------------------------------------------------------------------
extern "C" void kernel_launch(void* const* d_in, const int* in_sizes, int n_in,
                              void* d_out, int out_size, void* d_ws, size_t ws_size,
                              hipStream_t stream) {
    const float* img1 = (const float*)d_in[0];
    const float* img2 = (const float*)d_in[1];
    float* out = (float*)d_out;

    char* ws = (char*)d_ws;
    double*       sum = (double*)ws;              // 8 B
    unsigned int* mm  = (unsigned int*)(ws + 8);  // 8 B

    // Gaussian weights: f64 compute, normalize, cast to f32 (matches ref).
    G11 g;
    {
        double gd[WSZ], s = 0.0;
        for (int i = 0; i < WSZ; i++) {
            double d = (double)(i - WSZ / 2);
            gd[i] = std::exp(-(d * d) / (2.0 * 1.5 * 1.5));
            s += gd[i];
        }
        for (int i = 0; i < WSZ; i++) g.g[i] = (float)(gd[i] / s);
    }

    int n_img = 2 * DIN * DIN * DIN;  // 14,155,776

    k_init<<<1, 1, 0, stream>>>(mm, sum);
    k_minmax<<<2048, 256, 0, stream>>>((const float4*)img1, n_img / 4, mm);
    k_ssim<<<NBLK, 256, 0, stream>>>(img1, img2, mm, sum, g);
    k_final<<<1, 1, 0, stream>>>(sum, out);
}